// Round 15
// baseline (733.806 us; speedup 1.0000x reference)
//
#include <hip/hip_runtime.h>

// Spiking self-attention block (spikformer SSA), MI355X fp32 implementation.
// T=4 B=32 C=384 H=W=14 (N=196), heads=8, d=48.
//
// Exactness: LIF spikes are EXACTLY 0/1; attention is exact integer math.
// Conv GEMM: single fp32 accumulator per output, ascending K, fmaf per step
// (matched XLA bit-for-bit rounds 1-14). MFMA dead: any reorder flips spikes.
//
// R15: GEMM thread tile 8co x 16col (256 thr, tile 128co x 256col, BK16,
// R9 register-prefetch cadence). LDS-issue model (validated by 5 rounds at
// 67-73% VALU): 8x8 = 4 b128-issues / 64 MACs -> ceiling 67%; 8x16 =
// 6 issues / 128 MACs -> ceiling 89%. Failed variants audited: R6 = bounds
// cap, R7 = 16x4 tile (12.8 MACs/issue, WORSE), R11 = 128-thr occupancy,
// R12 = BK32 unroll-32 spill. This exact config never tested. b-cols as 4
// stride-64 quads (2-way bank alias = free); same ascending-c fmaf chain.
// Tripwire: WRITE_SIZE >150 MB = spill -> revert to R13 next round.
// k_mask / k_attn / lif4 = R8 verbatim.

#define T_ 4
#define B_ 32
#define C_ 384
#define N_ 196
#define NH_ 8
#define D_ 48
#define TB_ (T_ * B_)                 // 128
#define CN_ ((size_t)C_ * N_)         // 75264
#define BCN4_ (B_ * C_ * (N_ / 4))    // 602112 float4 units per (g,t)
#define TBCN_ ((size_t)T_ * B_ * C_ * N_)  // 9,633,792 floats
typedef unsigned long long u64;

// ---------------------------------------------------------------------------
// GEMM: Y[g][tb][co][n] = sum_c Wg[co][c] * X[tb][c][n]
// Cols flattened j = tb*196 + n; 25088 = 98 tiles of 256 (exact).
// Block: 128co x 256col, 256 thr, 8co x 16col per thread (col quads at
// stride 64). BK=16, register prefetch. grid: (98, 3, g).
// ---------------------------------------------------------------------------
__global__ __launch_bounds__(256) void gemm_f32(
    const float* __restrict__ X, const float* __restrict__ W0,
    const float* __restrict__ W1, const float* __restrict__ W2,
    float* __restrict__ P)
{
  const int g = blockIdx.z;
  const float* __restrict__ W = (g == 0) ? W0 : (g == 1) ? W1 : W2;
  const int co0 = blockIdx.y * 128;
  const int j0 = blockIdx.x * 256;
  __shared__ float As[16][128];   //  8 KB
  __shared__ float Bs[16][256];   // 16 KB
  const int tid = threadIdx.x;
  const int tx = tid & 15, ty = tid >> 4;

  // B staging: thread owns col quad bq4, k rows bk+{0,4,8,12}.
  const int bq4 = (tid & 63) * 4;
  const int bk = tid >> 6;                   // 0..3
  const int bj = j0 + bq4;
  const int btb = bj / N_;                   // quad never straddles tb
  const float* xb = X + (size_t)btb * CN_ + (bj - btb * N_);
  // A staging (R9): row arow, 8 floats at ac8.
  const int arow = tid >> 1;
  const int ac8 = (tid & 1) * 8;
  const float* wrow0 = W + (size_t)(co0 + arow) * C_ + ac8;

  // Prefetch tile 0.
  float4 pa0 = *(const float4*)(wrow0);
  float4 pa1 = *(const float4*)(wrow0 + 4);
  float4 pb[4];
#pragma unroll
  for (int q = 0; q < 4; ++q)
    pb[q] = *(const float4*)(xb + (size_t)(bk + 4 * q) * N_);

  float acc[8][16] = {};
  for (int c0 = 0; c0 < C_; c0 += 16) {
    __syncthreads();   // prev-iter readers done (no-op first iter)
    As[ac8 + 0][arow] = pa0.x; As[ac8 + 1][arow] = pa0.y;
    As[ac8 + 2][arow] = pa0.z; As[ac8 + 3][arow] = pa0.w;
    As[ac8 + 4][arow] = pa1.x; As[ac8 + 5][arow] = pa1.y;
    As[ac8 + 6][arow] = pa1.z; As[ac8 + 7][arow] = pa1.w;
#pragma unroll
    for (int q = 0; q < 4; ++q)
      *(float4*)&Bs[bk + 4 * q][bq4] = pb[q];
    __syncthreads();
    if (c0 + 16 < C_) {  // prefetch next tile during compute
      pa0 = *(const float4*)(wrow0 + c0 + 16);
      pa1 = *(const float4*)(wrow0 + c0 + 20);
#pragma unroll
      for (int q = 0; q < 4; ++q)
        pb[q] = *(const float4*)(xb + (size_t)(c0 + 16 + bk + 4 * q) * N_);
    }
#pragma unroll
    for (int k = 0; k < 16; ++k) {
      float a[8], b[16];
      *(float4*)&a[0] = *(const float4*)&As[k][ty * 4];        // broadcast
      *(float4*)&a[4] = *(const float4*)&As[k][64 + ty * 4];   // broadcast
#pragma unroll
      for (int q = 0; q < 4; ++q)
        *(float4*)&b[q * 4] = *(const float4*)&Bs[k][q * 64 + tx * 4];
#pragma unroll
      for (int i = 0; i < 8; ++i)
#pragma unroll
        for (int j = 0; j < 16; ++j)
          acc[i][j] = fmaf(a[i], b[j], acc[i][j]);
    }
  }
  // Epilogue: 4 col-quads x 8 rows of float4 stores (quads tb-safe).
#pragma unroll
  for (int q = 0; q < 4; ++q) {
    const int jj = j0 + q * 64 + tx * 4;
    const int tb = jj / N_;
    float* pbase = P + (size_t)(g * TB_ + tb) * CN_ + (jj - tb * N_);
#pragma unroll
    for (int rg = 0; rg < 2; ++rg) {
#pragma unroll
      for (int i = 0; i < 4; ++i) {
        const int r = rg * 4 + i;
        const int co = co0 + rg * 64 + ty * 4 + i;
        *(float4*)&pbase[(size_t)co * N_] = make_float4(
            acc[r][q * 4 + 0], acc[r][q * 4 + 1],
            acc[r][q * 4 + 2], acc[r][q * 4 + 3]);
      }
    }
  }
}

// ---------------------------------------------------------------------------
// Multi-step LIF over t with folded BN (final conv only).
// ---------------------------------------------------------------------------
__global__ __launch_bounds__(256) void lif4(
    const float* __restrict__ In, float* __restrict__ Out,
    const float* __restrict__ s0, const float* __restrict__ b0, float vth)
{
  const long u = (long)blockIdx.x * 256 + threadIdx.x;
  if (u >= BCN4_) return;
  const long r = u;
  const int c = (int)((r / (N_ / 4)) % C_);
  const bool has_bn = (s0 != nullptr);
  const float sc = has_bn ? s0[c] : 1.0f;
  const float bi = has_bn ? b0[c] : 0.0f;
  const float4* In4 = (const float4*)In;
  float4* Out4 = (float4*)Out;
  float v[4] = {0.f, 0.f, 0.f, 0.f};
#pragma unroll
  for (int t = 0; t < T_; ++t) {
    const long idx = (long)t * BCN4_ + r;
    const float4 y4 = In4[idx];
    float y[4] = {y4.x, y4.y, y4.z, y4.w};
    float o[4];
#pragma unroll
    for (int e = 0; e < 4; ++e) {
      const float yb = has_bn ? __fadd_rn(__fmul_rn(y[e], sc), bi) : y[e];
      v[e] = __fadd_rn(v[e], __fmul_rn(__fsub_rn(yb, v[e]), 0.5f));
      const bool fire = (v[e] >= vth);
      o[e] = fire ? 1.0f : 0.0f;
      v[e] = fire ? 0.0f : v[e];
    }
    Out4[idx] = make_float4(o[0], o[1], o[2], o[3]);
  }
}

// ---------------------------------------------------------------------------
// k_mask (R8): conv-LIF -> spike bitmasks. Wave-task = (g,h,b,j): 16 loads
// in flight, LIF recurrence, 16 ballots, lane0 stores 16 u64.
// MSK layout: [(h*32+b)][g][t][j][w]  (2304 u64 per (h,b)).
// ---------------------------------------------------------------------------
__global__ __launch_bounds__(256) void k_mask(
    const float* __restrict__ P, u64* __restrict__ MSK,
    const float* __restrict__ sq, const float* __restrict__ bq,
    const float* __restrict__ sk, const float* __restrict__ bk,
    const float* __restrict__ sv, const float* __restrict__ bv)
{
  const int wave = threadIdx.x >> 6, lane = threadIdx.x & 63;
  const int task = blockIdx.x * 4 + wave;      // 0..36863
  const int j = task % D_;
  int r = task / D_;
  const int b = r & 31; r >>= 5;
  const int h = r & 7;  r >>= 3;
  const int g = r;                              // 0..2
  const int c = h * D_ + j;
  const float sc = (g == 0 ? sq : g == 1 ? sk : sv)[c];
  const float bi = (g == 0 ? bq : g == 1 ? bk : bv)[c];
  const float* base = P + (size_t)g * TB_ * CN_ + (size_t)b * CN_ + (size_t)c * N_;

  float y[4][T_];
  bool act[4];
#pragma unroll
  for (int w = 0; w < 4; ++w) {
    const int m = w * 64 + lane;
    act[w] = (m < N_);
    const int mc = act[w] ? m : (N_ - 1);
#pragma unroll
    for (int t = 0; t < T_; ++t)
      y[w][t] = base[(size_t)t * B_ * CN_ + mc];   // 16 independent loads
  }
  u64* mb = MSK + ((size_t)(h * 32 + b) * 3 + g) * (T_ * D_ * 4) + j * 4;
  float v[4] = {0.f, 0.f, 0.f, 0.f};
#pragma unroll
  for (int t = 0; t < T_; ++t) {
#pragma unroll
    for (int w = 0; w < 4; ++w) {
      const float yb = __fadd_rn(__fmul_rn(y[w][t], sc), bi);
      v[w] = __fadd_rn(v[w], __fmul_rn(__fsub_rn(yb, v[w]), 0.5f));
      const bool fire = (v[w] >= 1.0f);
      if (fire) v[w] = 0.f;
      const u64 bl = __ballot(fire && act[w]);
      if (lane == 0) mb[(size_t)t * (D_ * 4) + w] = bl;
    }
  }
}

// ---------------------------------------------------------------------------
// k_attn (R8): per (h,b): masks to LDS, build qT + G bit-planes, apply
// out = sum_p 2^p popcount(qT & Gp[p][d]), attn-LIF, write binary spikes.
// ---------------------------------------------------------------------------
__global__ __launch_bounds__(1024) void k_attn(
    const u64* __restrict__ MSK, float* __restrict__ O)
{
  const int h = blockIdx.x;   // 8
  const int b = blockIdx.y;   // 32
  __shared__ u64 msk[3][T_][D_][4];   // 18432 B
  __shared__ u64 qT[T_][208];         // 6656 B
  __shared__ u64 Gp[T_][8][D_];       // 12288 B
  const int tid = threadIdx.x;
  const int wave = tid >> 6, lane = tid & 63;

  {
    const u64* ms = MSK + (size_t)(h * 32 + b) * 2304;
    u64* mf = &msk[0][0][0][0];
    for (int off = tid; off < 2304; off += 1024) mf[off] = ms[off];
  }
  __syncthreads();

  // qT[t][n] = q bits over j
  {
    const int t = wave >> 2, w = wave & 3;
    const int n = w * 64 + lane;
    u64 qr = 0ull;
#pragma unroll 8
    for (int j = 0; j < D_; ++j)
      qr |= ((msk[0][t][j][w] >> lane) & 1ull) << j;
    if (n < N_) qT[t][n] = qr;
  }
  // Gp[t][p][d]: bit-planes of G[j][d] = popcount_m(k_j & v_d), lanes=j
  for (int task = wave; task < T_ * D_; task += 16) {
    const int t = task / D_, d = task - (task / D_) * D_;
    const bool ja = (lane < D_);
    const int j = ja ? lane : (D_ - 1);
    const u64* kj = msk[1][t][j];
    const u64* vd = msk[2][t][d];
    const int gi = __popcll(kj[0] & vd[0]) + __popcll(kj[1] & vd[1]) +
                   __popcll(kj[2] & vd[2]) + __popcll(kj[3] & vd[3]);
#pragma unroll
    for (int p = 0; p < 8; ++p) {
      const u64 bl = __ballot(ja && ((gi >> p) & 1));
      if (lane == 0) Gp[t][p][d] = bl;
    }
  }
  __syncthreads();

  const int u = tid;
  if (u < 4 * N_) {
    const int dq = u / N_;
    const int n = u - dq * N_;
    const int d0 = dq * 12;
    float vmem[12];
#pragma unroll
    for (int i = 0; i < 12; ++i) vmem[i] = 0.f;
    for (int t = 0; t < T_; ++t) {
      const u64 qr = qT[t][n];
      float* ob = O + ((size_t)(t * B_ + b) * C_ + h * D_ + d0) * N_ + n;
#pragma unroll
      for (int i = 0; i < 12; ++i) {
        int acc = 0;
#pragma unroll
        for (int p = 0; p < 8; ++p)
          acc += __popcll(qr & Gp[t][p][d0 + i]) << p;
        const float y = __int2float_rn(acc) * 0.125f;  // exact
        vmem[i] = __fadd_rn(vmem[i], __fmul_rn(__fsub_rn(y, vmem[i]), 0.5f));
        const bool fire = (vmem[i] >= 0.5f);
        ob[(size_t)i * N_] = fire ? 1.0f : 0.0f;
        if (fire) vmem[i] = 0.f;
      }
    }
  }
}

// ---------------------------------------------------------------------------
extern "C" void kernel_launch(void* const* d_in, const int* in_sizes, int n_in,
                              void* d_out, int out_size, void* d_ws, size_t ws_size,
                              hipStream_t stream) {
  const float* x  = (const float*)d_in[0];
  const float* wq = (const float*)d_in[1];
  const float* sq = (const float*)d_in[2];
  const float* bq = (const float*)d_in[3];
  const float* wk = (const float*)d_in[4];
  const float* sk = (const float*)d_in[5];
  const float* bk = (const float*)d_in[6];
  const float* wv = (const float*)d_in[7];
  const float* sv = (const float*)d_in[8];
  const float* bv = (const float*)d_in[9];
  const float* wp = (const float*)d_in[10];
  const float* sp = (const float*)d_in[11];
  const float* bp = (const float*)d_in[12];
  float* out = (float*)d_out;

  float* P = (float*)d_ws;              // 3*TBCN qkv preacts
  float* O = P + 3 * TBCN_;             // TBCN attn spikes
  u64* MSK = (u64*)(P + 4 * TBCN_);     // 256 * 2304 u64 = 4.7 MB
  float* P2 = P;                        // final conv preact reuses q region

  gemm_f32<<<dim3(98, 3, 3), 256, 0, stream>>>(x, wq, wk, wv, P);
  k_mask<<<dim3(9216), 256, 0, stream>>>(P, MSK, sq, bq, sk, bk, sv, bv);
  k_attn<<<dim3(NH_, B_), 1024, 0, stream>>>(MSK, O);
  gemm_f32<<<dim3(98, 3, 1), 256, 0, stream>>>(O, wp, wp, wp, P2);
  lif4<<<dim3((BCN4_ + 255) / 256), 256, 0, stream>>>(P2, out, sp, bp, 1.0f);
}

// Round 16
// 649.226 us; speedup vs baseline: 1.1303x; 1.1303x over previous
//
#include <hip/hip_runtime.h>

// Spiking self-attention block (spikformer SSA), MI355X fp32 implementation.
// T=4 B=32 C=384 H=W=14 (N=196), heads=8, d=48.
//
// Exactness: LIF spikes are EXACTLY 0/1; attention is exact integer math.
// Conv GEMM: single fp32 accumulator per output, ascending K, fmaf per step
// (matched XLA bit-for-bit rounds 1-15). MFMA dead: any reorder flips spikes.
//
// R16: R15's 8co x 16col tile (89% LDS-issue ceiling vs 67% for 8x8) with
// the register budget fixed. R15 failed at VGPR 136 + AGPR 128 = 264 > 256
// total (gfx950 unified file) -> 1 wave/SIMD -> 10% occupancy. Fix: B is
// staged via global_load_lds (no VGPR round-trip; mechanism verified
// neutral-correct in R14), deleting the 16-reg B-prefetch + addressing
// -> total ~240 <= 256 -> 2 waves/SIMD (same residency as the 258-us
// baseline, 1.33x the VALU ceiling). One barrier per tile; B loads for
// tile i+1 fly across the ~4096-cyc compute window (>> 900-cyc HBM).
// Tripwire: occupancy <=12% or WRITE_SIZE >150 MB -> revert to R13.
// k_mask / k_attn / lif4 = R8 verbatim.

#define T_ 4
#define B_ 32
#define C_ 384
#define N_ 196
#define NH_ 8
#define D_ 48
#define TB_ (T_ * B_)                 // 128
#define CN_ ((size_t)C_ * N_)         // 75264
#define BCN4_ (B_ * C_ * (N_ / 4))    // 602112 float4 units per (g,t)
#define TBCN_ ((size_t)T_ * B_ * C_ * N_)  // 9,633,792 floats
typedef unsigned long long u64;

// ---------------------------------------------------------------------------
// GEMM: Y[g][tb][co][n] = sum_c Wg[co][c] * X[tb][c][n]
// Cols flattened j = tb*196 + n; 25088 = 98 tiles of 256 (exact).
// Block: 128co x 256col, 256 thr, 8co x 16col/thread (col quads stride 64).
// B: global_load_lds dbuf (wave w -> Bs rows {w,w+4,w+8,w+12}; lane l ->
//    cols 4l..4l+3; dest base wave-uniform, lane lands at base+16l).
// A: register prefetch one tile ahead + ds_write scatter, dbuf.
// grid: (98, 3, z).
// ---------------------------------------------------------------------------
__global__ __launch_bounds__(256) void gemm_f32(
    const float* __restrict__ X, const float* __restrict__ W0,
    const float* __restrict__ W1, const float* __restrict__ W2,
    float* __restrict__ P)
{
  const int g = blockIdx.z;
  const float* __restrict__ W = (g == 0) ? W0 : (g == 1) ? W1 : W2;
  const int co0 = blockIdx.y * 128;
  const int j0 = blockIdx.x * 256;
  __shared__ float As[2][16][128];   // 16 KB
  __shared__ float Bs[2][16][256];   // 32 KB
  const int tid = threadIdx.x;
  const int tx = tid & 15, ty = tid >> 4;
  const int wv = tid >> 6, lane = tid & 63;

  // B source: lane owns col quad 4*lane (never straddles tb; 196%4==0).
  const int bj = j0 + lane * 4;
  const int btb = bj / N_;
  const float* xcol = X + (size_t)btb * CN_ + (bj - btb * N_);
  // A staging: thread owns W[co0+arow][ac8..+7], scattered (transpose).
  const int arow = tid >> 1;
  const int ac8 = (tid & 1) * 8;
  const float* wrow0 = W + (size_t)(co0 + arow) * C_ + ac8;

  // ---- prologue: B tile0 async, A tile0 staged, A tile1 prefetched ----
#pragma unroll
  for (int q = 0; q < 4; ++q) {
    const int r = wv + 4 * q;
    __builtin_amdgcn_global_load_lds(
        (const __attribute__((address_space(1))) void*)(xcol + (size_t)r * N_),
        (__attribute__((address_space(3))) void*)&Bs[0][r][0], 16, 0, 0);
  }
  {
    const float4 a0 = *(const float4*)(wrow0);
    const float4 a1 = *(const float4*)(wrow0 + 4);
    As[0][ac8 + 0][arow] = a0.x; As[0][ac8 + 1][arow] = a0.y;
    As[0][ac8 + 2][arow] = a0.z; As[0][ac8 + 3][arow] = a0.w;
    As[0][ac8 + 4][arow] = a1.x; As[0][ac8 + 5][arow] = a1.y;
    As[0][ac8 + 6][arow] = a1.z; As[0][ac8 + 7][arow] = a1.w;
  }
  float4 n0 = *(const float4*)(wrow0 + 16);
  float4 n1 = *(const float4*)(wrow0 + 20);
  __syncthreads();   // drains B0 (vmcnt) + As0 writes (lgkm)

  float acc[8][16] = {};
  for (int i = 0; i < 24; ++i) {     // 384/16 c-tiles, ascending
    const int cur = i & 1, nxt = cur ^ 1;
    if (i < 23) {
      const int cb = (i + 1) * 16;
#pragma unroll
      for (int q = 0; q < 4; ++q) {  // B tile i+1, in flight across compute
        const int r = wv + 4 * q;
        __builtin_amdgcn_global_load_lds(
            (const __attribute__((address_space(1))) void*)(xcol + (size_t)(cb + r) * N_),
            (__attribute__((address_space(3))) void*)&Bs[nxt][r][0], 16, 0, 0);
      }
      As[nxt][ac8 + 0][arow] = n0.x; As[nxt][ac8 + 1][arow] = n0.y;
      As[nxt][ac8 + 2][arow] = n0.z; As[nxt][ac8 + 3][arow] = n0.w;
      As[nxt][ac8 + 4][arow] = n1.x; As[nxt][ac8 + 5][arow] = n1.y;
      As[nxt][ac8 + 6][arow] = n1.z; As[nxt][ac8 + 7][arow] = n1.w;
      if (i < 22) {  // prefetch A tile i+2
        n0 = *(const float4*)(wrow0 + (i + 2) * 16);
        n1 = *(const float4*)(wrow0 + (i + 2) * 16 + 4);
      }
    }
#pragma unroll
    for (int k = 0; k < 16; ++k) {
      float a[8], b[16];
      *(float4*)&a[0] = *(const float4*)&As[cur][k][ty * 4];        // bcast
      *(float4*)&a[4] = *(const float4*)&As[cur][k][64 + ty * 4];   // bcast
#pragma unroll
      for (int q = 0; q < 4; ++q)
        *(float4*)&b[q * 4] = *(const float4*)&Bs[cur][k][q * 64 + tx * 4];
#pragma unroll
      for (int ii = 0; ii < 8; ++ii)
#pragma unroll
        for (int jj = 0; jj < 16; ++jj)
          acc[ii][jj] = fmaf(a[ii], b[jj], acc[ii][jj]);
    }
    __syncthreads();  // one barrier/tile: readers done + nxt fully landed
  }
  // Epilogue: 4 col-quads x 8 rows of float4 stores (quads tb-safe).
#pragma unroll
  for (int q = 0; q < 4; ++q) {
    const int jj = j0 + q * 64 + tx * 4;
    const int tb = jj / N_;
    float* pbase = P + (size_t)(g * TB_ + tb) * CN_ + (jj - tb * N_);
#pragma unroll
    for (int rg = 0; rg < 2; ++rg) {
#pragma unroll
      for (int i = 0; i < 4; ++i) {
        const int r = rg * 4 + i;
        const int co = co0 + rg * 64 + ty * 4 + i;
        *(float4*)&pbase[(size_t)co * N_] = make_float4(
            acc[r][q * 4 + 0], acc[r][q * 4 + 1],
            acc[r][q * 4 + 2], acc[r][q * 4 + 3]);
      }
    }
  }
}

// ---------------------------------------------------------------------------
// Multi-step LIF over t with folded BN (final conv only).
// ---------------------------------------------------------------------------
__global__ __launch_bounds__(256) void lif4(
    const float* __restrict__ In, float* __restrict__ Out,
    const float* __restrict__ s0, const float* __restrict__ b0, float vth)
{
  const long u = (long)blockIdx.x * 256 + threadIdx.x;
  if (u >= BCN4_) return;
  const long r = u;
  const int c = (int)((r / (N_ / 4)) % C_);
  const bool has_bn = (s0 != nullptr);
  const float sc = has_bn ? s0[c] : 1.0f;
  const float bi = has_bn ? b0[c] : 0.0f;
  const float4* In4 = (const float4*)In;
  float4* Out4 = (float4*)Out;
  float v[4] = {0.f, 0.f, 0.f, 0.f};
#pragma unroll
  for (int t = 0; t < T_; ++t) {
    const long idx = (long)t * BCN4_ + r;
    const float4 y4 = In4[idx];
    float y[4] = {y4.x, y4.y, y4.z, y4.w};
    float o[4];
#pragma unroll
    for (int e = 0; e < 4; ++e) {
      const float yb = has_bn ? __fadd_rn(__fmul_rn(y[e], sc), bi) : y[e];
      v[e] = __fadd_rn(v[e], __fmul_rn(__fsub_rn(yb, v[e]), 0.5f));
      const bool fire = (v[e] >= vth);
      o[e] = fire ? 1.0f : 0.0f;
      v[e] = fire ? 0.0f : v[e];
    }
    Out4[idx] = make_float4(o[0], o[1], o[2], o[3]);
  }
}

// ---------------------------------------------------------------------------
// k_mask (R8): conv-LIF -> spike bitmasks. Wave-task = (g,h,b,j): 16 loads
// in flight, LIF recurrence, 16 ballots, lane0 stores 16 u64.
// MSK layout: [(h*32+b)][g][t][j][w]  (2304 u64 per (h,b)).
// ---------------------------------------------------------------------------
__global__ __launch_bounds__(256) void k_mask(
    const float* __restrict__ P, u64* __restrict__ MSK,
    const float* __restrict__ sq, const float* __restrict__ bq,
    const float* __restrict__ sk, const float* __restrict__ bk,
    const float* __restrict__ sv, const float* __restrict__ bv)
{
  const int wave = threadIdx.x >> 6, lane = threadIdx.x & 63;
  const int task = blockIdx.x * 4 + wave;      // 0..36863
  const int j = task % D_;
  int r = task / D_;
  const int b = r & 31; r >>= 5;
  const int h = r & 7;  r >>= 3;
  const int g = r;                              // 0..2
  const int c = h * D_ + j;
  const float sc = (g == 0 ? sq : g == 1 ? sk : sv)[c];
  const float bi = (g == 0 ? bq : g == 1 ? bk : bv)[c];
  const float* base = P + (size_t)g * TB_ * CN_ + (size_t)b * CN_ + (size_t)c * N_;

  float y[4][T_];
  bool act[4];
#pragma unroll
  for (int w = 0; w < 4; ++w) {
    const int m = w * 64 + lane;
    act[w] = (m < N_);
    const int mc = act[w] ? m : (N_ - 1);
#pragma unroll
    for (int t = 0; t < T_; ++t)
      y[w][t] = base[(size_t)t * B_ * CN_ + mc];   // 16 independent loads
  }
  u64* mb = MSK + ((size_t)(h * 32 + b) * 3 + g) * (T_ * D_ * 4) + j * 4;
  float v[4] = {0.f, 0.f, 0.f, 0.f};
#pragma unroll
  for (int t = 0; t < T_; ++t) {
#pragma unroll
    for (int w = 0; w < 4; ++w) {
      const float yb = __fadd_rn(__fmul_rn(y[w][t], sc), bi);
      v[w] = __fadd_rn(v[w], __fmul_rn(__fsub_rn(yb, v[w]), 0.5f));
      const bool fire = (v[w] >= 1.0f);
      if (fire) v[w] = 0.f;
      const u64 bl = __ballot(fire && act[w]);
      if (lane == 0) mb[(size_t)t * (D_ * 4) + w] = bl;
    }
  }
}

// ---------------------------------------------------------------------------
// k_attn (R8): per (h,b): masks to LDS, build qT + G bit-planes, apply
// out = sum_p 2^p popcount(qT & Gp[p][d]), attn-LIF, write binary spikes.
// ---------------------------------------------------------------------------
__global__ __launch_bounds__(1024) void k_attn(
    const u64* __restrict__ MSK, float* __restrict__ O)
{
  const int h = blockIdx.x;   // 8
  const int b = blockIdx.y;   // 32
  __shared__ u64 msk[3][T_][D_][4];   // 18432 B
  __shared__ u64 qT[T_][208];         // 6656 B
  __shared__ u64 Gp[T_][8][D_];       // 12288 B
  const int tid = threadIdx.x;
  const int wave = tid >> 6, lane = tid & 63;

  {
    const u64* ms = MSK + (size_t)(h * 32 + b) * 2304;
    u64* mf = &msk[0][0][0][0];
    for (int off = tid; off < 2304; off += 1024) mf[off] = ms[off];
  }
  __syncthreads();

  // qT[t][n] = q bits over j
  {
    const int t = wave >> 2, w = wave & 3;
    const int n = w * 64 + lane;
    u64 qr = 0ull;
#pragma unroll 8
    for (int j = 0; j < D_; ++j)
      qr |= ((msk[0][t][j][w] >> lane) & 1ull) << j;
    if (n < N_) qT[t][n] = qr;
  }
  // Gp[t][p][d]: bit-planes of G[j][d] = popcount_m(k_j & v_d), lanes=j
  for (int task = wave; task < T_ * D_; task += 16) {
    const int t = task / D_, d = task - (task / D_) * D_;
    const bool ja = (lane < D_);
    const int j = ja ? lane : (D_ - 1);
    const u64* kj = msk[1][t][j];
    const u64* vd = msk[2][t][d];
    const int gi = __popcll(kj[0] & vd[0]) + __popcll(kj[1] & vd[1]) +
                   __popcll(kj[2] & vd[2]) + __popcll(kj[3] & vd[3]);
#pragma unroll
    for (int p = 0; p < 8; ++p) {
      const u64 bl = __ballot(ja && ((gi >> p) & 1));
      if (lane == 0) Gp[t][p][d] = bl;
    }
  }
  __syncthreads();

  const int u = tid;
  if (u < 4 * N_) {
    const int dq = u / N_;
    const int n = u - dq * N_;
    const int d0 = dq * 12;
    float vmem[12];
#pragma unroll
    for (int i = 0; i < 12; ++i) vmem[i] = 0.f;
    for (int t = 0; t < T_; ++t) {
      const u64 qr = qT[t][n];
      float* ob = O + ((size_t)(t * B_ + b) * C_ + h * D_ + d0) * N_ + n;
#pragma unroll
      for (int i = 0; i < 12; ++i) {
        int acc = 0;
#pragma unroll
        for (int p = 0; p < 8; ++p)
          acc += __popcll(qr & Gp[t][p][d0 + i]) << p;
        const float y = __int2float_rn(acc) * 0.125f;  // exact
        vmem[i] = __fadd_rn(vmem[i], __fmul_rn(__fsub_rn(y, vmem[i]), 0.5f));
        const bool fire = (vmem[i] >= 0.5f);
        ob[(size_t)i * N_] = fire ? 1.0f : 0.0f;
        if (fire) vmem[i] = 0.f;
      }
    }
  }
}

// ---------------------------------------------------------------------------
extern "C" void kernel_launch(void* const* d_in, const int* in_sizes, int n_in,
                              void* d_out, int out_size, void* d_ws, size_t ws_size,
                              hipStream_t stream) {
  const float* x  = (const float*)d_in[0];
  const float* wq = (const float*)d_in[1];
  const float* sq = (const float*)d_in[2];
  const float* bq = (const float*)d_in[3];
  const float* wk = (const float*)d_in[4];
  const float* sk = (const float*)d_in[5];
  const float* bk = (const float*)d_in[6];
  const float* wv = (const float*)d_in[7];
  const float* sv = (const float*)d_in[8];
  const float* bv = (const float*)d_in[9];
  const float* wp = (const float*)d_in[10];
  const float* sp = (const float*)d_in[11];
  const float* bp = (const float*)d_in[12];
  float* out = (float*)d_out;

  float* P = (float*)d_ws;              // 3*TBCN qkv preacts
  float* O = P + 3 * TBCN_;             // TBCN attn spikes
  u64* MSK = (u64*)(P + 4 * TBCN_);     // 256 * 2304 u64 = 4.7 MB
  float* P2 = P;                        // final conv preact reuses q region

  gemm_f32<<<dim3(98, 3, 3), 256, 0, stream>>>(x, wq, wk, wv, P);
  k_mask<<<dim3(9216), 256, 0, stream>>>(P, MSK, sq, bq, sk, bk, sv, bv);
  k_attn<<<dim3(NH_, B_), 1024, 0, stream>>>(MSK, O);
  gemm_f32<<<dim3(98, 3, 1), 256, 0, stream>>>(O, wp, wp, wp, P2);
  lif4<<<dim3((BCN4_ + 255) / 256), 256, 0, stream>>>(P2, out, sp, bp, 1.0f);
}

// Round 17
// 521.578 us; speedup vs baseline: 1.4069x; 1.2447x over previous
//
#include <hip/hip_runtime.h>

// Spiking self-attention block (spikformer SSA), MI355X fp32 implementation.
// T=4 B=32 C=384 H=W=14 (N=196), heads=8, d=48.
//
// Exactness: LIF spikes are EXACTLY 0/1; attention is exact integer math.
// Conv GEMM: single fp32 accumulator per output, ascending K, fmaf per step
// (matched XLA bit-for-bit rounds 1-16). MFMA dead: any reorder flips spikes.
//
// R17 = R13 verbatim (best measured: 503.2 us). Final configuration.
// GEMM design space exhausted on-HW: 8x8/256thr/BK16+reg-prefetch = 258 us
// (LDS-issue plateau, VALU ~71%); all larger tiles (R6/R7/R11/R12/R15/R16)
// collapse to 1 wave/SIMD via the 256-reg unified-file limit (acc>64 regs
// + staging > 256 total), measured 320-440 us. Chain (k_mask/k_attn) is
// HBM-bound + small, stable ~130 us incl. gaps across R8/R13/R14.

#define T_ 4
#define B_ 32
#define C_ 384
#define N_ 196
#define NH_ 8
#define D_ 48
#define TB_ (T_ * B_)                 // 128
#define CN_ ((size_t)C_ * N_)         // 75264
#define BCN4_ (B_ * C_ * (N_ / 4))    // 602112 float4 units per (g,t)
#define TBCN_ ((size_t)T_ * B_ * C_ * N_)  // 9,633,792 floats
typedef unsigned long long u64;

// ---------------------------------------------------------------------------
// GEMM: Y[g][tb][co][n] = sum_c W[co][c]*X[tb][c][n]
// Cols flattened j = tb*196 + n; 25088 = 196 tiles of 128 (exact).
// Block: 128co x 128col, 256 thr, 8x8/thread in two stride-64 quads.
// BK=16 + register prefetch. grid: (196, 3, g).
// ---------------------------------------------------------------------------
__global__ __launch_bounds__(256) void gemm_f32(
    const float* __restrict__ X, const float* __restrict__ W0,
    const float* __restrict__ W1, const float* __restrict__ W2,
    float* __restrict__ P)
{
  const int g = blockIdx.z;
  const float* __restrict__ W = (g == 0) ? W0 : (g == 1) ? W1 : W2;
  const int co0 = blockIdx.y * 128;
  const int j0 = blockIdx.x * 128;
  __shared__ float As[16][128];
  __shared__ float Bs[16][128];
  const int tid = threadIdx.x;
  const int tx = tid & 15, ty = tid >> 4;

  const int bcol = (tid & 31) * 4;
  const int bk = tid >> 5;
  const int bj = j0 + bcol;
  const int btb = bj / N_;
  const float* xb = X + (size_t)btb * CN_ + (bj - btb * N_);
  const int arow = tid >> 1;
  const int ac8 = (tid & 1) * 8;
  const float* wrow0 = W + (size_t)(co0 + arow) * C_ + ac8;

  // Prefetch tile 0 into registers.
  float4 pa0 = *(const float4*)(wrow0);
  float4 pa1 = *(const float4*)(wrow0 + 4);
  float4 pb0 = *(const float4*)(xb + (size_t)bk * N_);
  float4 pb1 = *(const float4*)(xb + (size_t)(bk + 8) * N_);

  float acc[8][8] = {};
  for (int c0 = 0; c0 < C_; c0 += 16) {
    __syncthreads();   // prev-iter readers done (no-op on first iter)
    As[ac8 + 0][arow] = pa0.x; As[ac8 + 1][arow] = pa0.y;
    As[ac8 + 2][arow] = pa0.z; As[ac8 + 3][arow] = pa0.w;
    As[ac8 + 4][arow] = pa1.x; As[ac8 + 5][arow] = pa1.y;
    As[ac8 + 6][arow] = pa1.z; As[ac8 + 7][arow] = pa1.w;
    *(float4*)&Bs[bk][bcol] = pb0;
    *(float4*)&Bs[bk + 8][bcol] = pb1;
    __syncthreads();
    if (c0 + 16 < C_) {  // prefetch next tile; latency hidden by compute below
      pa0 = *(const float4*)(wrow0 + c0 + 16);
      pa1 = *(const float4*)(wrow0 + c0 + 20);
      pb0 = *(const float4*)(xb + (size_t)(c0 + 16 + bk) * N_);
      pb1 = *(const float4*)(xb + (size_t)(c0 + 24 + bk) * N_);
    }
#pragma unroll
    for (int k = 0; k < 16; ++k) {
      float a[8], b[8];
      *(float4*)&a[0] = *(const float4*)&As[k][ty * 4];
      *(float4*)&a[4] = *(const float4*)&As[k][64 + ty * 4];
      *(float4*)&b[0] = *(const float4*)&Bs[k][tx * 4];
      *(float4*)&b[4] = *(const float4*)&Bs[k][64 + tx * 4];
#pragma unroll
      for (int i = 0; i < 8; ++i)
#pragma unroll
        for (int j = 0; j < 8; ++j)
          acc[i][j] = fmaf(a[i], b[j], acc[i][j]);
    }
  }
#pragma unroll
  for (int cg = 0; cg < 2; ++cg) {
    const int jj = j0 + cg * 64 + tx * 4;
    const int tb = jj / N_;
    float* pb = P + (size_t)(g * TB_ + tb) * CN_ + (jj - tb * N_);
#pragma unroll
    for (int rg = 0; rg < 2; ++rg) {
#pragma unroll
      for (int i = 0; i < 4; ++i) {
        const int r = rg * 4 + i;
        const int co = co0 + rg * 64 + ty * 4 + i;
        *(float4*)&pb[(size_t)co * N_] = make_float4(
            acc[r][cg * 4 + 0], acc[r][cg * 4 + 1],
            acc[r][cg * 4 + 2], acc[r][cg * 4 + 3]);
      }
    }
  }
}

// ---------------------------------------------------------------------------
// Multi-step LIF over t with folded BN (final conv only).
// ---------------------------------------------------------------------------
__global__ __launch_bounds__(256) void lif4(
    const float* __restrict__ In, float* __restrict__ Out,
    const float* __restrict__ s0, const float* __restrict__ b0, float vth)
{
  const long u = (long)blockIdx.x * 256 + threadIdx.x;
  if (u >= BCN4_) return;
  const long r = u;
  const int c = (int)((r / (N_ / 4)) % C_);
  const bool has_bn = (s0 != nullptr);
  const float sc = has_bn ? s0[c] : 1.0f;
  const float bi = has_bn ? b0[c] : 0.0f;
  const float4* In4 = (const float4*)In;
  float4* Out4 = (float4*)Out;
  float v[4] = {0.f, 0.f, 0.f, 0.f};
#pragma unroll
  for (int t = 0; t < T_; ++t) {
    const long idx = (long)t * BCN4_ + r;
    const float4 y4 = In4[idx];
    float y[4] = {y4.x, y4.y, y4.z, y4.w};
    float o[4];
#pragma unroll
    for (int e = 0; e < 4; ++e) {
      const float yb = has_bn ? __fadd_rn(__fmul_rn(y[e], sc), bi) : y[e];
      v[e] = __fadd_rn(v[e], __fmul_rn(__fsub_rn(yb, v[e]), 0.5f));
      const bool fire = (v[e] >= vth);
      o[e] = fire ? 1.0f : 0.0f;
      v[e] = fire ? 0.0f : v[e];
    }
    Out4[idx] = make_float4(o[0], o[1], o[2], o[3]);
  }
}

// ---------------------------------------------------------------------------
// k_mask (R8): conv-LIF -> spike bitmasks. Wave-task = (g,h,b,j): 16 loads
// in flight, LIF recurrence, 16 ballots, lane0 stores 16 u64.
// MSK layout: [(h*32+b)][g][t][j][w]  (2304 u64 per (h,b)).
// ---------------------------------------------------------------------------
__global__ __launch_bounds__(256) void k_mask(
    const float* __restrict__ P, u64* __restrict__ MSK,
    const float* __restrict__ sq, const float* __restrict__ bq,
    const float* __restrict__ sk, const float* __restrict__ bk,
    const float* __restrict__ sv, const float* __restrict__ bv)
{
  const int wave = threadIdx.x >> 6, lane = threadIdx.x & 63;
  const int task = blockIdx.x * 4 + wave;      // 0..36863
  const int j = task % D_;
  int r = task / D_;
  const int b = r & 31; r >>= 5;
  const int h = r & 7;  r >>= 3;
  const int g = r;                              // 0..2
  const int c = h * D_ + j;
  const float sc = (g == 0 ? sq : g == 1 ? sk : sv)[c];
  const float bi = (g == 0 ? bq : g == 1 ? bk : bv)[c];
  const float* base = P + (size_t)g * TB_ * CN_ + (size_t)b * CN_ + (size_t)c * N_;

  float y[4][T_];
  bool act[4];
#pragma unroll
  for (int w = 0; w < 4; ++w) {
    const int m = w * 64 + lane;
    act[w] = (m < N_);
    const int mc = act[w] ? m : (N_ - 1);
#pragma unroll
    for (int t = 0; t < T_; ++t)
      y[w][t] = base[(size_t)t * B_ * CN_ + mc];   // 16 independent loads
  }
  u64* mb = MSK + ((size_t)(h * 32 + b) * 3 + g) * (T_ * D_ * 4) + j * 4;
  float v[4] = {0.f, 0.f, 0.f, 0.f};
#pragma unroll
  for (int t = 0; t < T_; ++t) {
#pragma unroll
    for (int w = 0; w < 4; ++w) {
      const float yb = __fadd_rn(__fmul_rn(y[w][t], sc), bi);
      v[w] = __fadd_rn(v[w], __fmul_rn(__fsub_rn(yb, v[w]), 0.5f));
      const bool fire = (v[w] >= 1.0f);
      if (fire) v[w] = 0.f;
      const u64 bl = __ballot(fire && act[w]);
      if (lane == 0) mb[(size_t)t * (D_ * 4) + w] = bl;
    }
  }
}

// ---------------------------------------------------------------------------
// k_attn (R8): per (h,b): masks to LDS, build qT + G bit-planes, apply
// out = sum_p 2^p popcount(qT & Gp[p][d]), attn-LIF, write binary spikes.
// ---------------------------------------------------------------------------
__global__ __launch_bounds__(1024) void k_attn(
    const u64* __restrict__ MSK, float* __restrict__ O)
{
  const int h = blockIdx.x;   // 8
  const int b = blockIdx.y;   // 32
  __shared__ u64 msk[3][T_][D_][4];   // 18432 B
  __shared__ u64 qT[T_][208];         // 6656 B
  __shared__ u64 Gp[T_][8][D_];       // 12288 B
  const int tid = threadIdx.x;
  const int wave = tid >> 6, lane = tid & 63;

  {
    const u64* ms = MSK + (size_t)(h * 32 + b) * 2304;
    u64* mf = &msk[0][0][0][0];
    for (int off = tid; off < 2304; off += 1024) mf[off] = ms[off];
  }
  __syncthreads();

  // qT[t][n] = q bits over j
  {
    const int t = wave >> 2, w = wave & 3;
    const int n = w * 64 + lane;
    u64 qr = 0ull;
#pragma unroll 8
    for (int j = 0; j < D_; ++j)
      qr |= ((msk[0][t][j][w] >> lane) & 1ull) << j;
    if (n < N_) qT[t][n] = qr;
  }
  // Gp[t][p][d]: bit-planes of G[j][d] = popcount_m(k_j & v_d), lanes=j
  for (int task = wave; task < T_ * D_; task += 16) {
    const int t = task / D_, d = task - (task / D_) * D_;
    const bool ja = (lane < D_);
    const int j = ja ? lane : (D_ - 1);
    const u64* kj = msk[1][t][j];
    const u64* vd = msk[2][t][d];
    const int gi = __popcll(kj[0] & vd[0]) + __popcll(kj[1] & vd[1]) +
                   __popcll(kj[2] & vd[2]) + __popcll(kj[3] & vd[3]);
#pragma unroll
    for (int p = 0; p < 8; ++p) {
      const u64 bl = __ballot(ja && ((gi >> p) & 1));
      if (lane == 0) Gp[t][p][d] = bl;
    }
  }
  __syncthreads();

  const int u = tid;
  if (u < 4 * N_) {
    const int dq = u / N_;
    const int n = u - dq * N_;
    const int d0 = dq * 12;
    float vmem[12];
#pragma unroll
    for (int i = 0; i < 12; ++i) vmem[i] = 0.f;
    for (int t = 0; t < T_; ++t) {
      const u64 qr = qT[t][n];
      float* ob = O + ((size_t)(t * B_ + b) * C_ + h * D_ + d0) * N_ + n;
#pragma unroll
      for (int i = 0; i < 12; ++i) {
        int acc = 0;
#pragma unroll
        for (int p = 0; p < 8; ++p)
          acc += __popcll(qr & Gp[t][p][d0 + i]) << p;
        const float y = __int2float_rn(acc) * 0.125f;  // exact
        vmem[i] = __fadd_rn(vmem[i], __fmul_rn(__fsub_rn(y, vmem[i]), 0.5f));
        const bool fire = (vmem[i] >= 0.5f);
        ob[(size_t)i * N_] = fire ? 1.0f : 0.0f;
        if (fire) vmem[i] = 0.f;
      }
    }
  }
}

// ---------------------------------------------------------------------------
extern "C" void kernel_launch(void* const* d_in, const int* in_sizes, int n_in,
                              void* d_out, int out_size, void* d_ws, size_t ws_size,
                              hipStream_t stream) {
  const float* x  = (const float*)d_in[0];
  const float* wq = (const float*)d_in[1];
  const float* sq = (const float*)d_in[2];
  const float* bq = (const float*)d_in[3];
  const float* wk = (const float*)d_in[4];
  const float* sk = (const float*)d_in[5];
  const float* bk = (const float*)d_in[6];
  const float* wv = (const float*)d_in[7];
  const float* sv = (const float*)d_in[8];
  const float* bv = (const float*)d_in[9];
  const float* wp = (const float*)d_in[10];
  const float* sp = (const float*)d_in[11];
  const float* bp = (const float*)d_in[12];
  float* out = (float*)d_out;

  float* P = (float*)d_ws;              // 3*TBCN qkv preacts
  float* O = P + 3 * TBCN_;             // TBCN attn spikes
  u64* MSK = (u64*)(P + 4 * TBCN_);     // 256 * 2304 u64 = 4.7 MB
  float* P2 = P;                        // final conv preact reuses q region

  gemm_f32<<<dim3(196, 3, 3), 256, 0, stream>>>(x, wq, wk, wv, P);
  k_mask<<<dim3(9216), 256, 0, stream>>>(P, MSK, sq, bq, sk, bk, sv, bv);
  k_attn<<<dim3(NH_, B_), 1024, 0, stream>>>(MSK, O);
  gemm_f32<<<dim3(196, 3, 1), 256, 0, stream>>>(O, wp, wp, wp, P2);
  lif4<<<dim3((BCN4_ + 255) / 256), 256, 0, stream>>>(P2, out, sp, bp, 1.0f);
}